// Round 9
// baseline (769.973 us; speedup 1.0000x reference)
//
#include <hip/hip_runtime.h>
#include <stdint.h>

typedef unsigned int uint;
typedef unsigned short ushort;
typedef unsigned long long u64;

#define B_   8192
#define D_   128
#define N_   64
#define L_   3

typedef __attribute__((ext_vector_type(8))) short short8;
typedef __attribute__((ext_vector_type(4))) float f32x4;
union FragU { uint4 u; short8 h; };

__device__ __forceinline__ float bf2f(ushort u){ union{uint i; float f;} c; c.i=((uint)u)<<16; return c.f; }
__device__ __forceinline__ float bflo(uint u){ union{uint i; float f;} c; c.i=u<<16; return c.f; }
__device__ __forceinline__ float bfhi(uint u){ union{uint i; float f;} c; c.i=u&0xffff0000u; return c.f; }
__device__ __forceinline__ ushort f2bf(float f){ uint u=__float_as_uint(f); return (ushort)((u + 0x7fffu + ((u>>16)&1u))>>16); }
__device__ __forceinline__ uint pk2(float lo, float hi){ return (uint)f2bf(lo) | (((uint)f2bf(hi))<<16); }
__device__ __forceinline__ float wsum(float v){ for (int o=32;o;o>>=1) v += __shfl_xor(v,o); return v; }

// ---------------- static device storage for folded weights ----------------
__device__ ushort g_WqT[3*128*128];
__device__ ushort g_WkT[3*128*128];
__device__ ushort g_WvT[3*128*128];
__device__ ushort g_WoT[3*128*128];
__device__ ushort g_W1T[3*512*128];
__device__ ushort g_W2T[3*128*512];
__device__ ushort g_egoT[128*128];
__device__ ushort g_outT[128*128];
__device__ float  g_npRec[128*12];   // [j][12]: w0..w5, npb, npg, npbb, pad (16B-aligned rows)
__device__ ushort g_bqF[384];
__device__ ushort g_bkF[384];
__device__ ushort g_bvF[384];
__device__ ushort g_b1F[1536];

// ---------------- LDS layout (bytes) ----------------
#define OFF_X   0        // x residual: f32 [16][130]  (stride 520 B)
#define XSTR    520
#define OFF_XH  8320     // A operand bf16 [16][136]   (stride 272 B)
#define XHSTR   272
#define OFF_Q   12672    // Q bf16 [16][130] (stride 260 B)
#define QSTR    260
#define OFF_QK  16832    // qk bf16 [16][136] (rows 8..15 zeroed once)
#define QKSTR   272
#define OFF_QB  21184    // qb f32 [16] (rows 8..15 zero)
#define OFF_V   21248    // valid flags f32 [64]
#define OFF_NB  21504    // nbhat n-major bf16 [64][136]
#define NBSTR   272
#define OFF_NT  38912    // nbhat d-major bf16 [128][72]
#define NTSTR   144
#define OFF_AT  57344    // attn bf16 [16][72]
#define ATSTR   144
#define OFF_U   59648    // U bf16 [8][136] (stride 272; rows=h, cols=d)
#define USTR    272
#define OFF_CXH 61824    // ctx bf16 [128] (256 B)
#define OFF_MSK 62080    // u64 [16] per-batch valid masks (slack region)
#define OFF_H1  21504    // h1 bf16 [16][520] — aliases NB region (FFN phase only)
#define LDS_SZ  62272

struct P {
  const float *ego, *epos, *evel, *npos, *nvel;
  const int   *mask;
  const float *npW, *npb, *npg, *npbb;
  const float *ego_b, *ego_g, *ego_bb;
  const float *bo, *b2, *out_b, *out_g, *out_bb;
  ushort *nbg;           // dense nbhat n-major, 16 KB per batch
  float *outp;
};

// ---------------- prep_all: weights only (fold/transpose + npRec) ----------------
// grid roles: [0,2688) prepF, [2688,3712) prepP, 3712 prepNp
__global__ __launch_bounds__(256,4) void prep_all(P p,
    const float* Wq,const float* bq,const float* n1g,const float* n1b,
    const float* Wk,const float* bk,const float* nkg,const float* nkb,
    const float* Wv,const float* bv,
    const float* W1,const float* b1,const float* n2g,const float* n2b,
    const float* Wo,const float* W2,const float* egoW,const float* outW){
  __shared__ float red[2];
  const int bid = blockIdx.x;
  const int tid = threadIdx.x;
  if (bid < 2688){
    int t = tid;
    const float *src,*g,*bb,*bias; ushort *dstW,*dstB; int N;
    if (bid<384){ int l=bid>>7, j=bid&127; src=Wq+l*16384+j; g=n1g+l*128; bb=n1b+l*128; bias=bq+l*128+j; dstW=g_WqT+l*16384+j*128; dstB=g_bqF+l*128+j; N=128; }
    else if (bid<768){ int q=bid-384; int l=q>>7, j=q&127; src=Wk+l*16384+j; g=nkg+l*128; bb=nkb+l*128; bias=bk+l*128+j; dstW=g_WkT+l*16384+j*128; dstB=g_bkF+l*128+j; N=128; }
    else if (bid<1152){ int q=bid-768; int l=q>>7, j=q&127; src=Wv+l*16384+j; g=nkg+l*128; bb=nkb+l*128; bias=bv+l*128+j; dstW=g_WvT+l*16384+j*128; dstB=g_bvF+l*128+j; N=128; }
    else { int q=bid-1152; int l=q/512, j=q%512; src=W1+l*65536+j; g=n2g+l*128; bb=n2b+l*128; bias=b1+l*512+j; dstW=g_W1T+l*65536+j*128; dstB=g_b1F+l*512+j; N=512; }
    if (t<128){
      float wv = src[t*N];
      dstW[t] = f2bf(g[t]*wv);
      float pv = wsum(bb[t]*wv);
      if ((t&63)==0) red[t>>6]=pv;
    }
    __syncthreads();
    if (t==0) *dstB = f2bf(red[0]+red[1]+bias[0]);
  } else if (bid < 3712){
    int pb = bid - 2688, t = tid;
    if (t<128){
      if (pb<384){ int l=pb>>7, j=pb&127; g_WoT[l*16384+j*128+t] = f2bf(Wo[l*16384+t*128+j]); }
      else if (pb<768){ int q=pb-384; int l=q>>7, j=q&127;
        for (int k=t;k<512;k+=128) g_W2T[l*65536+j*512+k] = f2bf(W2[l*65536+k*128+j]); }
      else if (pb<896){ int j=pb-768; g_egoT[j*128+t]=f2bf(egoW[t*128+j]); }
      else { int j=pb-896; g_outT[j*128+t]=f2bf(outW[t*128+j]); }
    }
  } else {
    int t = tid;
    if (t<128){
      for (int r=0;r<6;++r) g_npRec[t*12+r]=p.npW[r*128+t];
      g_npRec[t*12+6]=p.npb[t]; g_npRec[t*12+7]=p.npg[t]; g_npRec[t*12+8]=p.npbb[t];
      g_npRec[t*12+9]=0.f; g_npRec[t*12+10]=0.f; g_npRec[t*12+11]=0.f;
    }
  }
}

// ---------------- shared helpers ----------------
__device__ __forceinline__ void ln_to_xh(char* smem, int tid){
  int b = tid>>4, pp = tid&15;
  const char* xr = smem + OFF_X + b*XSTR + pp*32;
  float v[8];
  #pragma unroll
  for (int i=0;i<4;++i){ float2 t2 = *(const float2*)(xr + i*8); v[2*i]=t2.x; v[2*i+1]=t2.y; }
  float s1=0.f, s2=0.f;
  #pragma unroll
  for (int i=0;i<8;++i){ s1+=v[i]; s2+=v[i]*v[i]; }
  for (int o=1;o<16;o<<=1){ s1 += __shfl_xor(s1,o); s2 += __shfl_xor(s2,o); }
  float m = s1*0.0078125f, rs = rsqrtf(s2*0.0078125f - m*m + 1e-5f);
  uint4 o4;
  o4.x = pk2((v[0]-m)*rs,(v[1]-m)*rs); o4.y = pk2((v[2]-m)*rs,(v[3]-m)*rs);
  o4.z = pk2((v[4]-m)*rs,(v[5]-m)*rs); o4.w = pk2((v[6]-m)*rs,(v[7]-m)*rs);
  *(uint4*)(smem + OFF_XH + b*XHSTR + pp*16) = o4;
}

__device__ __forceinline__ void ln_affine_inplace(char* smem, int tid, const float* g, const float* bb){
  int b = tid>>4, pp = tid&15;
  char* xr = smem + OFF_X + b*XSTR + pp*32;
  float v[8];
  #pragma unroll
  for (int i=0;i<4;++i){ float2 t2 = *(const float2*)(xr + i*8); v[2*i]=t2.x; v[2*i+1]=t2.y; }
  float s1=0.f, s2=0.f;
  #pragma unroll
  for (int i=0;i<8;++i){ s1+=v[i]; s2+=v[i]*v[i]; }
  for (int o=1;o<16;o<<=1){ s1 += __shfl_xor(s1,o); s2 += __shfl_xor(s2,o); }
  float m = s1*0.0078125f, rs = rsqrtf(s2*0.0078125f - m*m + 1e-5f);
  #pragma unroll
  for (int i=0;i<8;++i) v[i] = (v[i]-m)*rs*g[pp*8+i] + bb[pp*8+i];
  #pragma unroll
  for (int i=0;i<4;++i){ float2 t2; t2.x=v[2*i]; t2.y=v[2*i+1]; *(float2*)(xr + i*8) = t2; }
}

__device__ __forceinline__ void cvt_x_to_xh(char* smem, int tid){
  int b = tid>>4, pp = tid&15;
  const char* xr = smem + OFF_X + b*XSTR + pp*32;
  float v[8];
  #pragma unroll
  for (int i=0;i<4;++i){ float2 t2 = *(const float2*)(xr + i*8); v[2*i]=t2.x; v[2*i+1]=t2.y; }
  uint4 o4;
  o4.x=pk2(v[0],v[1]); o4.y=pk2(v[2],v[3]); o4.z=pk2(v[4],v[5]); o4.w=pk2(v[6],v[7]);
  *(uint4*)(smem + OFF_XH + b*XHSTR + pp*16) = o4;
}

// compress even bits of a u64 -> u32 (morton compaction)
__device__ __forceinline__ uint evenbits(u64 x){
  x &= 0x5555555555555555ULL;
  x = (x | (x>>1))  & 0x3333333333333333ULL;
  x = (x | (x>>2))  & 0x0F0F0F0F0F0F0F0FULL;
  x = (x | (x>>4))  & 0x00FF00FF00FF00FFULL;
  x = (x | (x>>8))  & 0x0000FFFF0000FFFFULL;
  x = (x | (x>>16)) & 0x00000000FFFFFFFFULL;
  return (uint)x;
}

// ================= st_main7: r8-verified structure + fused nb staging + staged-load reorder =================
__global__ __launch_bounds__(256,2) void st_main7(P p){
  __shared__ __align__(16) char smem[LDS_SZ];
  const int tid = threadIdx.x;
  const int w = tid>>6, l64 = tid&63;
  const int cc = l64&15, qq = l64>>4;
  const int bB = blockIdx.x*16;

  // ---- Phase 0: compute nbhat for this block's 16 batches -> ws; masks -> LDS ----
  {
    const int g = tid>>7, t = tid&127;
    const int nn = t>>1, jh = t&1;
    const int half = t>>6;           // 0: n 0..31, 1: n 32..63
    for (int pass=0; pass<8; ++pass){
      const int bl = pass*2+g;
      const int b = bB + bl;
      float2 pn = ((const float2*)p.npos)[b*N_+nn];
      float2 vn = ((const float2*)p.nvel)[b*N_+nn];
      float2 pe = ((const float2*)p.epos)[b];
      float2 ve = ((const float2*)p.evel)[b];
      float rx=pn.x-pe.x, ry=pn.y-pe.y, rvx=vn.x-ve.x, rvy=vn.y-ve.y;
      float nrm = sqrtf(rx*rx+ry*ry);
      float dist = fmaxf(nrm,1e-6f), bear = atan2f(ry+1e-8f, rx+1e-8f);
      bool vld = (p.mask[b*N_+nn]!=0) && (nrm<3.0f);
      float z[64]; float sa=0.f, sb=0.f;
      #pragma unroll
      for (int jj=0;jj<64;++jj){
        const float* rec = g_npRec + (jh*64+jj)*12;
        float4 r0 = *(const float4*)rec;
        float4 r1 = *(const float4*)(rec+4);
        float v = r1.z + rx*r0.x + ry*r0.y + rvx*r0.z + rvy*r0.w + dist*r1.x + bear*r1.y;
        z[jj]=v; sa+=v; sb+=v*v;
      }
      sa += __shfl_xor(sa,1); sb += __shfl_xor(sb,1);
      float m1 = sa*0.0078125f, r1s = rsqrtf(sb*0.0078125f - m1*m1 + 1e-5f);
      float ta=0.f, tb=0.f;
      #pragma unroll
      for (int jj=0;jj<64;++jj){
        const float* rec = g_npRec + (jh*64+jj)*12;
        float a = (z[jj]-m1)*r1s*rec[7] + rec[8];
        a = fmaxf(a,0.f);
        z[jj]=a; ta+=a; tb+=a*a;
      }
      ta += __shfl_xor(ta,1); tb += __shfl_xor(tb,1);
      float m2 = ta*0.0078125f, r2s = rsqrtf(tb*0.0078125f - m2*m2 + 1e-5f);
      // thread t owns a contiguous 128B run (nn*256 + jh*128 == t*128) of the 16KB batch slot
      uint4* dst4 = (uint4*)((char*)p.nbg + (size_t)b*16384 + (size_t)t*128);
      #pragma unroll
      for (int q8=0;q8<8;++q8){
        uint prs[4];
        #pragma unroll
        for (int qi=0;qi<4;++qi){
          int q = q8*4+qi;
          prs[qi] = pk2((z[2*q]-m2)*r2s, (z[2*q+1]-m2)*r2s);
        }
        uint4 ov; ov.x=prs[0]; ov.y=prs[1]; ov.z=prs[2]; ov.w=prs[3];
        dst4[q8] = ov;
      }
      // per-wave valid mask: ballot has vld(n) at even lane 2*(n - half*32)
      uint m32 = evenbits(__ballot(vld));
      if (l64==0) *(uint*)(smem + OFF_MSK + bl*8 + half*4) = m32;
    }
  }
  __syncthreads();  // masks visible; nbg stores drained (vmcnt 0 at barrier)

  // one-time zeroing: qk rows (all; 8..15 stay 0), qb, attn rows 8..15
  for (int i=tid;i<1088;i+=256) ((uint*)(smem+OFF_QK))[i]=0u;
  if (tid<16) ((float*)(smem+OFF_QB))[tid]=0.f;
  for (int i=tid;i<288;i+=256) ((uint*)(smem+OFF_AT+8*ATSTR))[i]=0u;

  // ego: cvt input -> xh
  {
    int b_=tid>>4, pp=tid&15;
    const float* src = p.ego + (size_t)(bB+b_)*128 + pp*8;
    float4 v0 = *(const float4*)src, v1 = *(const float4*)(src+4);
    uint4 o4; o4.x=pk2(v0.x,v0.y); o4.y=pk2(v0.z,v0.w); o4.z=pk2(v1.x,v1.y); o4.w=pk2(v1.z,v1.w);
    *(uint4*)(smem + OFF_XH + b_*XHSTR + pp*16) = o4;
  }
  __syncthreads();
  // ego GEMM -> x (f32, +ego_b)
  {
    #pragma unroll
    for (int i=0;i<2;++i){
      int nt = w*2+i;
      f32x4 acc = {0.f,0.f,0.f,0.f};
      #pragma unroll
      for (int kt=0;kt<4;++kt){
        FragU a,bF;
        a.u = *(const uint4*)(smem + OFF_XH + cc*XHSTR + kt*64 + qq*16);
        bF.u = *(const uint4*)(g_egoT + (nt*16+cc)*128 + kt*32 + qq*8);
        acc = __builtin_amdgcn_mfma_f32_16x16x32_bf16(a.h, bF.h, acc, 0,0,0);
      }
      int col = nt*16+cc;
      float bv = p.ego_b[col];
      #pragma unroll
      for (int r=0;r<4;++r) *(float*)(smem+OFF_X+(qq*4+r)*XSTR+col*4) = acc[r]+bv;
    }
  }
  __syncthreads();
  ln_affine_inplace(smem, tid, p.ego_g, p.ego_bb);
  __syncthreads();

  for (int li=0; li<L_; ++li){
    // LN(x) -> xh (n1 folded)
    ln_to_xh(smem, tid);
    __syncthreads();
    // Q GEMM
    {
      const ushort* W = g_WqT + li*16384;
      #pragma unroll
      for (int i=0;i<2;++i){
        int nt = w*2+i;
        f32x4 acc = {0.f,0.f,0.f,0.f};
        #pragma unroll
        for (int kt=0;kt<4;++kt){
          FragU a,bF;
          a.u = *(const uint4*)(smem + OFF_XH + cc*XHSTR + kt*64 + qq*16);
          bF.u = *(const uint4*)(W + (nt*16+cc)*128 + kt*32 + qq*8);
          acc = __builtin_amdgcn_mfma_f32_16x16x32_bf16(a.h, bF.h, acc, 0,0,0);
        }
        int col = nt*16+cc;
        float bv = bf2f(g_bqF[li*128+col]);
        ushort* Qm = (ushort*)(smem+OFF_Q);
        #pragma unroll
        for (int r=0;r<4;++r) Qm[(qq*4+r)*130 + col] = f2bf(acc[r]+bv);
      }
    }
    __syncthreads();

    // ---- attention rounds: 1 batch per round, 4 waves cooperate ----
    for (int bl=0; bl<16; ++bl){
      const int b = bB + bl;
      const int n = w*16 + (l64>>2), seg = l64&3;
      // issue staging loads into regs (latency hides under qk fold)
      uint4 nv[4];
      {
        const uint4* src = (const uint4*)(p.nbg + (size_t)b*8192 + n*128);
        #pragma unroll
        for (int i=0;i<4;++i) nv[i] = src[seg + i*4];
        if (seg==0){
          u64 mv = *(const u64*)(smem + OFF_MSK + bl*8);
          *(float*)(smem+OFF_V+n*4) = ((mv>>n)&1ULL) ? 1.f : 0.f;
        }
      }
      // qk fold: qk[h][d] = sum_j WkT'[h16+j][d] * Q[bl][h16+j]; qb[h]
      {
        int h = (w<<1) + (l64>>5);
        int d4 = (l64&31)*4;
        const ushort* Wk = g_WkT + li*16384;
        float a0=0.f,a1=0.f,a2=0.f,a3=0.f, qb=0.f;
        #pragma unroll
        for (int j=0;j<16;++j){
          float qv = bf2f(*(const ushort*)(smem + OFF_Q + bl*QSTR + (h*16+j)*2));
          uint2 wv = *(const uint2*)(Wk + (h*16+j)*128 + d4);
          a0 += qv*bflo(wv.x); a1 += qv*bfhi(wv.x);
          a2 += qv*bflo(wv.y); a3 += qv*bfhi(wv.y);
          qb += qv * bf2f(g_bkF[li*128 + h*16 + j]);
        }
        uint2 o; o.x = pk2(a0,a1); o.y = pk2(a2,a3);
        *(uint2*)(smem + OFF_QK + h*QKSTR + d4*2) = o;
        if ((l64&31)==0) *(float*)(smem+OFF_QB + h*4) = qb;
      }
      // commit staged nb (NB copy + NT transpose)
      {
        ushort* T = (ushort*)(smem+OFF_NT);
        #pragma unroll
        for (int i=0;i<4;++i){
          int ci = seg + i*4;
          uint4 v = nv[i];
          *(uint4*)(smem + OFF_NB + n*NBSTR + ci*16) = v;
          int d0 = ci*8;
          T[(d0+0)*72+n]=(ushort)v.x; T[(d0+1)*72+n]=(ushort)(v.x>>16);
          T[(d0+2)*72+n]=(ushort)v.y; T[(d0+3)*72+n]=(ushort)(v.y>>16);
          T[(d0+4)*72+n]=(ushort)v.z; T[(d0+5)*72+n]=(ushort)(v.z>>16);
          T[(d0+6)*72+n]=(ushort)v.w; T[(d0+7)*72+n]=(ushort)(v.w>>16);
        }
      }
      __syncthreads();

      // scores^T = nbhat @ qk^T via MFMA (redundant on 4 waves), softmax
      {
        FragU bfr[4];
        #pragma unroll
        for (int kt=0;kt<4;++kt) bfr[kt].u = *(const uint4*)(smem + OFF_QK + cc*QKSTR + kt*64 + qq*16);
        f32x4 c[4];
        #pragma unroll
        for (int mt=0;mt<4;++mt){
          f32x4 acc = {0.f,0.f,0.f,0.f};
          #pragma unroll
          for (int kt=0;kt<4;++kt){
            FragU a; a.u = *(const uint4*)(smem + OFF_NB + (mt*16+cc)*NBSTR + kt*64 + qq*16);
            acc = __builtin_amdgcn_mfma_f32_16x16x32_bf16(a.h, bfr[kt].h, acc, 0,0,0);
          }
          c[mt]=acc;
        }
        float qbv = *(const float*)(smem+OFF_QB+cc*4);
        float fl[16]; float anyv=0.f;
        #pragma unroll
        for (int mt=0;mt<4;++mt)
          #pragma unroll
          for (int r=0;r<4;++r){
            int nb_ = mt*16 + qq*4 + r;
            float f = *(const float*)(smem+OFF_V+nb_*4);
            fl[mt*4+r]=f; anyv+=f;
          }
        bool none = (__ballot(anyv>0.5f)==0ULL);
        float sc[16];
        #pragma unroll
        for (int mt=0;mt<4;++mt)
          #pragma unroll
          for (int r=0;r<4;++r){
            int k = mt*4+r; int nb_ = mt*16+qq*4+r;
            bool ok = (fl[k]>0.5f) || (none && nb_==0);
            sc[k] = ok ? 0.25f*(c[mt][r]+qbv) : -1e9f;
          }
        float mx=-3e38f;
        #pragma unroll
        for (int k=0;k<16;++k) mx=fmaxf(mx,sc[k]);
        mx = fmaxf(mx,__shfl_xor(mx,16)); mx = fmaxf(mx,__shfl_xor(mx,32));
        float ex[16]; float se=0.f;
        #pragma unroll
        for (int k=0;k<16;++k){ ex[k]=__expf(sc[k]-mx); se+=ex[k]; }
        se += __shfl_xor(se,16); se += __shfl_xor(se,32);
        float inv = 1.f/se;
        if (w==0 && cc<8){
          ushort* A = (ushort*)(smem+OFF_AT);
          #pragma unroll
          for (int mt=0;mt<4;++mt)
            #pragma unroll
            for (int r=0;r<4;++r) A[cc*72 + (mt*16+qq*4+r)] = f2bf(ex[mt*4+r]*inv);
        }
      }
      __syncthreads();

      // U = attn @ nbhat via MFMA (B from transposed copy) -> U[h][d] bf16, stride 272
      {
        #pragma unroll
        for (int i=0;i<2;++i){
          int nt = w*2 + i;
          f32x4 acc={0.f,0.f,0.f,0.f};
          #pragma unroll
          for (int kt=0;kt<2;++kt){
            FragU a,bF;
            a.u = *(const uint4*)(smem + OFF_AT + cc*ATSTR + kt*64 + qq*16);
            bF.u = *(const uint4*)(smem + OFF_NT + (nt*16+cc)*NTSTR + kt*64 + qq*16);
            acc = __builtin_amdgcn_mfma_f32_16x16x32_bf16(a.h, bF.h, acc, 0,0,0);
          }
          if (qq<2){
            ushort* U = (ushort*)(smem+OFF_U);
            #pragma unroll
            for (int r=0;r<4;++r) U[(qq*4+r)*136 + nt*16+cc] = f2bf(acc[r]);
          }
        }
      }
      __syncthreads();

      // ctx via MFMA: D[h][j] = sum_d U[h,d]*WvT'[j,d]; extract diag block h = nt
      {
        FragU afr[4];
        #pragma unroll
        for (int kt=0;kt<4;++kt)
          afr[kt].u = *(const uint4*)(smem + OFF_U + (cc&7)*USTR + kt*64 + qq*16);
        #pragma unroll
        for (int i=0;i<2;++i){
          int nt = w*2+i;           // == head h for this column tile
          f32x4 acc={0.f,0.f,0.f,0.f};
          #pragma unroll
          for (int kt=0;kt<4;++kt){
            FragU bF; bF.u = *(const uint4*)(g_WvT + li*16384 + (nt*16+cc)*128 + kt*32 + qq*8);
            acc = __builtin_amdgcn_mfma_f32_16x16x32_bf16(afr[kt].h, bF.h, acc, 0,0,0);
          }
          if (qq == (nt>>2)){
            int j = nt*16+cc;
            ((ushort*)(smem+OFF_CXH))[j] = f2bf(acc[nt&3] + bf2f(g_bvF[li*128+j]));
          }
        }
      }
      __syncthreads();

      // x[bl] += cx @ WoT + bo via MFMA (A broadcast: all lanes read same cxh fragment)
      {
        FragU afr[4];
        #pragma unroll
        for (int kt=0;kt<4;++kt)
          afr[kt].u = *(const uint4*)(smem + OFF_CXH + kt*64 + qq*16);
        #pragma unroll
        for (int i=0;i<2;++i){
          int nt = w*2+i;
          f32x4 acc={0.f,0.f,0.f,0.f};
          #pragma unroll
          for (int kt=0;kt<4;++kt){
            FragU bF; bF.u = *(const uint4*)(g_WoT + li*16384 + (nt*16+cc)*128 + kt*32 + qq*8);
            acc = __builtin_amdgcn_mfma_f32_16x16x32_bf16(afr[kt].h, bF.h, acc, 0,0,0);
          }
          if (qq==0){
            int j = nt*16+cc;
            *(float*)(smem + OFF_X + bl*XSTR + j*4) += acc[0] + p.bo[li*128+j];
          }
        }
      }
      __syncthreads();
    } // rounds

    // FFN: LN(x) -> xh (n2 folded)
    ln_to_xh(smem, tid);
    __syncthreads();
    // W1 GEMM + gelu -> h1
    {
      FragU afr[4];
      #pragma unroll
      for (int kt=0;kt<4;++kt) afr[kt].u = *(const uint4*)(smem+OFF_XH + cc*XHSTR + kt*64 + qq*16);
      const ushort* W = g_W1T + li*65536;
      ushort* H = (ushort*)(smem+OFF_H1);
      #pragma unroll
      for (int i=0;i<8;++i){
        int nt = w*8+i;
        f32x4 acc={0.f,0.f,0.f,0.f};
        #pragma unroll
        for (int kt=0;kt<4;++kt){
          FragU bF; bF.u = *(const uint4*)(W + (nt*16+cc)*128 + kt*32 + qq*8);
          acc = __builtin_amdgcn_mfma_f32_16x16x32_bf16(afr[kt].h, bF.h, acc, 0,0,0);
        }
        int col = nt*16+cc;
        float bv = bf2f(g_b1F[li*512+col]);
        #pragma unroll
        for (int r=0;r<4;++r){
          float v = acc[r]+bv;
          v = 0.5f*v*(1.f+erff(v*0.70710678118654752f));
          H[(qq*4+r)*520 + col] = f2bf(v);
        }
      }
    }
    __syncthreads();
    // W2 GEMM -> x +=
    {
      const ushort* W = g_W2T + li*65536;
      #pragma unroll
      for (int i=0;i<2;++i){
        int nt = w*2+i;
        f32x4 acc={0.f,0.f,0.f,0.f};
        #pragma unroll
        for (int kt=0;kt<16;++kt){
          FragU a,bF;
          a.u = *(const uint4*)(smem+OFF_H1 + cc*1040 + kt*64 + qq*16);
          bF.u = *(const uint4*)(W + (nt*16+cc)*512 + kt*32 + qq*8);
          acc = __builtin_amdgcn_mfma_f32_16x16x32_bf16(a.h, bF.h, acc, 0,0,0);
        }
        int col = nt*16+cc;
        float bv = p.b2[li*128+col];
        #pragma unroll
        for (int r=0;r<4;++r){
          float* xp = (float*)(smem+OFF_X+(qq*4+r)*XSTR+col*4);
          *xp += acc[r]+bv;
        }
      }
    }
    __syncthreads();
  } // layers

  // output: LN(x @ outW + out_b)
  cvt_x_to_xh(smem, tid);
  __syncthreads();
  {
    #pragma unroll
    for (int i=0;i<2;++i){
      int nt = w*2+i;
      f32x4 acc = {0.f,0.f,0.f,0.f};
      #pragma unroll
      for (int kt=0;kt<4;++kt){
        FragU a,bF;
        a.u = *(const uint4*)(smem + OFF_XH + cc*XHSTR + kt*64 + qq*16);
        bF.u = *(const uint4*)(g_outT + (nt*16+cc)*128 + kt*32 + qq*8);
        acc = __builtin_amdgcn_mfma_f32_16x16x32_bf16(a.h, bF.h, acc, 0,0,0);
      }
      int col = nt*16+cc;
      float bv = p.out_b[col];
      #pragma unroll
      for (int r=0;r<4;++r) *(float*)(smem+OFF_X+(qq*4+r)*XSTR+col*4) = acc[r]+bv;
    }
  }
  __syncthreads();
  {
    int b_=tid>>4, pp=tid&15;
    const char* xr = smem + OFF_X + b_*XSTR + pp*32;
    float v[8];
    #pragma unroll
    for (int i=0;i<4;++i){ float2 t2 = *(const float2*)(xr + i*8); v[2*i]=t2.x; v[2*i+1]=t2.y; }
    float s1=0.f, s2=0.f;
    #pragma unroll
    for (int i=0;i<8;++i){ s1+=v[i]; s2+=v[i]*v[i]; }
    for (int o=1;o<16;o<<=1){ s1 += __shfl_xor(s1,o); s2 += __shfl_xor(s2,o); }
    float m = s1*0.0078125f, rs = rsqrtf(s2*0.0078125f - m*m + 1e-5f);
    float4 o0,o1;
    o0.x=(v[0]-m)*rs*p.out_g[pp*8+0]+p.out_bb[pp*8+0];
    o0.y=(v[1]-m)*rs*p.out_g[pp*8+1]+p.out_bb[pp*8+1];
    o0.z=(v[2]-m)*rs*p.out_g[pp*8+2]+p.out_bb[pp*8+2];
    o0.w=(v[3]-m)*rs*p.out_g[pp*8+3]+p.out_bb[pp*8+3];
    o1.x=(v[4]-m)*rs*p.out_g[pp*8+4]+p.out_bb[pp*8+4];
    o1.y=(v[5]-m)*rs*p.out_g[pp*8+5]+p.out_bb[pp*8+5];
    o1.z=(v[6]-m)*rs*p.out_g[pp*8+6]+p.out_bb[pp*8+6];
    o1.w=(v[7]-m)*rs*p.out_g[pp*8+7]+p.out_bb[pp*8+7];
    float* dst = p.outp + (size_t)(bB+b_)*128 + pp*8;
    *(float4*)dst = o0; *(float4*)(dst+4) = o1;
  }
}

// ================= fallback main kernel (inline nb compute per round; small ws) =================
__global__ __launch_bounds__(256,2) void st_main0(P p){
  __shared__ __align__(16) char smem[LDS_SZ];
  const int tid = threadIdx.x;
  const int w = tid>>6, l64 = tid&63;
  const int cc = l64&15, qq = l64>>4;
  const int bB = blockIdx.x*16;

  for (int i=tid;i<1088;i+=256) ((uint*)(smem+OFF_QK))[i]=0u;
  if (tid<16) ((float*)(smem+OFF_QB))[tid]=0.f;
  for (int i=tid;i<288;i+=256) ((uint*)(smem+OFF_AT+8*ATSTR))[i]=0u;

  {
    int b_=tid>>4, pp=tid&15;
    const float* src = p.ego + (size_t)(bB+b_)*128 + pp*8;
    float4 v0 = *(const float4*)src, v1 = *(const float4*)(src+4);
    uint4 o4; o4.x=pk2(v0.x,v0.y); o4.y=pk2(v0.z,v0.w); o4.z=pk2(v1.x,v1.y); o4.w=pk2(v1.z,v1.w);
    *(uint4*)(smem + OFF_XH + b_*XHSTR + pp*16) = o4;
  }
  __syncthreads();
  {
    #pragma unroll
    for (int i=0;i<2;++i){
      int nt = w*2+i;
      f32x4 acc = {0.f,0.f,0.f,0.f};
      #pragma unroll
      for (int kt=0;kt<4;++kt){
        FragU a,bF;
        a.u = *(const uint4*)(smem + OFF_XH + cc*XHSTR + kt*64 + qq*16);
        bF.u = *(const uint4*)(g_egoT + (nt*16+cc)*128 + kt*32 + qq*8);
        acc = __builtin_amdgcn_mfma_f32_16x16x32_bf16(a.h, bF.h, acc, 0,0,0);
      }
      int col = nt*16+cc;
      float bv = p.ego_b[col];
      #pragma unroll
      for (int r=0;r<4;++r) *(float*)(smem+OFF_X+(qq*4+r)*XSTR+col*4) = acc[r]+bv;
    }
  }
  __syncthreads();
  ln_affine_inplace(smem, tid, p.ego_g, p.ego_bb);
  __syncthreads();

  for (int li=0; li<L_; ++li){
    ln_to_xh(smem, tid);
    __syncthreads();
    {
      const ushort* W = g_WqT + li*16384;
      #pragma unroll
      for (int i=0;i<2;++i){
        int nt = w*2+i;
        f32x4 acc = {0.f,0.f,0.f,0.f};
        #pragma unroll
        for (int kt=0;kt<4;++kt){
          FragU a,bF;
          a.u = *(const uint4*)(smem + OFF_XH + cc*XHSTR + kt*64 + qq*16);
          bF.u = *(const uint4*)(W + (nt*16+cc)*128 + kt*32 + qq*8);
          acc = __builtin_amdgcn_mfma_f32_16x16x32_bf16(a.h, bF.h, acc, 0,0,0);
        }
        int col = nt*16+cc;
        float bv = bf2f(g_bqF[li*128+col]);
        ushort* Qm = (ushort*)(smem+OFF_Q);
        #pragma unroll
        for (int r=0;r<4;++r) Qm[(qq*4+r)*130 + col] = f2bf(acc[r]+bv);
      }
    }
    __syncthreads();

    for (int bl=0; bl<16; ++bl){
      const int b = bB + bl;
      {
        int n = w*16 + (l64>>2), jq = l64&3;
        float2 pn = ((const float2*)p.npos)[b*N_+n];
        float2 vn = ((const float2*)p.nvel)[b*N_+n];
        float2 pe = ((const float2*)p.epos)[b];
        float2 ve = ((const float2*)p.evel)[b];
        float rx=pn.x-pe.x, ry=pn.y-pe.y, rvx=vn.x-ve.x, rvy=vn.y-ve.y;
        float nrm = sqrtf(rx*rx+ry*ry);
        float dist = fmaxf(nrm,1e-6f), bear = atan2f(ry+1e-8f, rx+1e-8f);
        if (jq==0){
          bool vld = (p.mask[b*N_+n]!=0) && (nrm<3.0f);
          *(float*)(smem+OFF_V+n*4) = vld?1.f:0.f;
        }
        float z[32]; float sa=0.f, sb=0.f;
        #pragma unroll
        for (int jj=0;jj<32;++jj){
          const float* rec = g_npRec + (jq*32+jj)*12;
          float4 r0 = *(const float4*)rec;
          float4 r1 = *(const float4*)(rec+4);
          float v = r1.z + rx*r0.x + ry*r0.y + rvx*r0.z + rvy*r0.w + dist*r1.x + bear*r1.y;
          z[jj]=v; sa+=v; sb+=v*v;
        }
        sa += __shfl_xor(sa,1); sb += __shfl_xor(sb,1);
        sa += __shfl_xor(sa,2); sb += __shfl_xor(sb,2);
        float m1 = sa*0.0078125f, r1s = rsqrtf(sb*0.0078125f - m1*m1 + 1e-5f);
        float ta=0.f, tb=0.f;
        #pragma unroll
        for (int jj=0;jj<32;++jj){
          const float* rec = g_npRec + (jq*32+jj)*12;
          float a = (z[jj]-m1)*r1s*rec[7] + rec[8];
          a = fmaxf(a,0.f);
          z[jj]=a; ta+=a; tb+=a*a;
        }
        ta += __shfl_xor(ta,1); tb += __shfl_xor(tb,1);
        ta += __shfl_xor(ta,2); tb += __shfl_xor(tb,2);
        float m2 = ta*0.0078125f, r2s = rsqrtf(tb*0.0078125f - m2*m2 + 1e-5f);
        ushort* T = (ushort*)(smem+OFF_NT);
        #pragma unroll
        for (int q2=0;q2<16;++q2){
          uint pr = pk2((z[2*q2]-m2)*r2s, (z[2*q2+1]-m2)*r2s);
          *(uint*)(smem + OFF_NB + n*NBSTR + jq*64 + q2*4) = pr;
          int d = jq*32 + q2*2;
          T[d*72 + n] = (ushort)pr;
          T[(d+1)*72 + n] = (ushort)(pr>>16);
        }
      }
      {
        int h = (w<<1) + (l64>>5);
        int d4 = (l64&31)*4;
        const ushort* Wk = g_WkT + li*16384;
        float a0=0.f,a1=0.f,a2=0.f,a3=0.f, qb=0.f;
        #pragma unroll
        for (int j=0;j<16;++j){
          float qv = bf2f(*(const ushort*)(smem + OFF_Q + bl*QSTR + (h*16+j)*2));
          uint2 wv = *(const uint2*)(Wk + (h*16+j)*128 + d4);
          a0 += qv*bflo(wv.x); a1 += qv*bfhi(wv.x);
          a2 += qv*bflo(wv.y); a3 += qv*bfhi(wv.y);
          qb += qv * bf2f(g_bkF[li*128 + h*16 + j]);
        }
        uint2 o; o.x = pk2(a0,a1); o.y = pk2(a2,a3);
        *(uint2*)(smem + OFF_QK + h*QKSTR + d4*2) = o;
        if ((l64&31)==0) *(float*)(smem+OFF_QB + h*4) = qb;
      }
      __syncthreads();

      {
        FragU bfr[4];
        #pragma unroll
        for (int kt=0;kt<4;++kt) bfr[kt].u = *(const uint4*)(smem + OFF_QK + cc*QKSTR + kt*64 + qq*16);
        f32x4 c[4];
        #pragma unroll
        for (int mt=0;mt<4;++mt){
          f32x4 acc = {0.f,0.f,0.f,0.f};
          #pragma unroll
          for (int kt=0;kt<4;++kt){
            FragU a; a.u = *(const uint4*)(smem + OFF_NB + (mt*16+cc)*NBSTR + kt*64 + qq*16);
            acc = __builtin_amdgcn_mfma_f32_16x16x32_bf16(a.h, bfr[kt].h, acc, 0,0,0);
          }
          c[mt]=acc;
        }
        float qbv = *(const float*)(smem+OFF_QB+cc*4);
        float fl[16]; float anyv=0.f;
        #pragma unroll
        for (int mt=0;mt<4;++mt)
          #pragma unroll
          for (int r=0;r<4;++r){
            int n = mt*16 + qq*4 + r;
            float f = *(const float*)(smem+OFF_V+n*4);
            fl[mt*4+r]=f; anyv+=f;
          }
        bool none = (__ballot(anyv>0.5f)==0ULL);
        float sc[16];
        #pragma unroll
        for (int mt=0;mt<4;++mt)
          #pragma unroll
          for (int r=0;r<4;++r){
            int k = mt*4+r; int n = mt*16+qq*4+r;
            bool ok = (fl[k]>0.5f) || (none && n==0);
            sc[k] = ok ? 0.25f*(c[mt][r]+qbv) : -1e9f;
          }
        float mx=-3e38f;
        #pragma unroll
        for (int k=0;k<16;++k) mx=fmaxf(mx,sc[k]);
        mx = fmaxf(mx,__shfl_xor(mx,16)); mx = fmaxf(mx,__shfl_xor(mx,32));
        float ex[16]; float se=0.f;
        #pragma unroll
        for (int k=0;k<16;++k){ ex[k]=__expf(sc[k]-mx); se+=ex[k]; }
        se += __shfl_xor(se,16); se += __shfl_xor(se,32);
        float inv = 1.f/se;
        if (w==0 && cc<8){
          ushort* A = (ushort*)(smem+OFF_AT);
          #pragma unroll
          for (int mt=0;mt<4;++mt)
            #pragma unroll
            for (int r=0;r<4;++r) A[cc*72 + (mt*16+qq*4+r)] = f2bf(ex[mt*4+r]*inv);
        }
      }
      __syncthreads();

      {
        #pragma unroll
        for (int i=0;i<2;++i){
          int nt = w*2 + i;
          f32x4 acc={0.f,0.f,0.f,0.f};
          #pragma unroll
          for (int kt=0;kt<2;++kt){
            FragU a,bF;
            a.u = *(const uint4*)(smem + OFF_AT + cc*ATSTR + kt*64 + qq*16);
            bF.u = *(const uint4*)(smem + OFF_NT + (nt*16+cc)*NTSTR + kt*64 + qq*16);
            acc = __builtin_amdgcn_mfma_f32_16x16x32_bf16(a.h, bF.h, acc, 0,0,0);
          }
          if (qq<2){
            ushort* U = (ushort*)(smem+OFF_U);
            #pragma unroll
            for (int r=0;r<4;++r) U[(qq*4+r)*136 + nt*16+cc] = f2bf(acc[r]);
          }
        }
      }
      __syncthreads();

      {
        FragU afr[4];
        #pragma unroll
        for (int kt=0;kt<4;++kt)
          afr[kt].u = *(const uint4*)(smem + OFF_U + (cc&7)*USTR + kt*64 + qq*16);
        #pragma unroll
        for (int i=0;i<2;++i){
          int nt = w*2+i;
          f32x4 acc={0.f,0.f,0.f,0.f};
          #pragma unroll
          for (int kt=0;kt<4;++kt){
            FragU bF; bF.u = *(const uint4*)(g_WvT + li*16384 + (nt*16+cc)*128 + kt*32 + qq*8);
            acc = __builtin_amdgcn_mfma_f32_16x16x32_bf16(afr[kt].h, bF.h, acc, 0,0,0);
          }
          if (qq == (nt>>2)){
            int j = nt*16+cc;
            ((ushort*)(smem+OFF_CXH))[j] = f2bf(acc[nt&3] + bf2f(g_bvF[li*128+j]));
          }
        }
      }
      __syncthreads();

      {
        FragU afr[4];
        #pragma unroll
        for (int kt=0;kt<4;++kt)
          afr[kt].u = *(const uint4*)(smem + OFF_CXH + kt*64 + qq*16);
        #pragma unroll
        for (int i=0;i<2;++i){
          int nt = w*2+i;
          f32x4 acc={0.f,0.f,0.f,0.f};
          #pragma unroll
          for (int kt=0;kt<4;++kt){
            FragU bF; bF.u = *(const uint4*)(g_WoT + li*16384 + (nt*16+cc)*128 + kt*32 + qq*8);
            acc = __builtin_amdgcn_mfma_f32_16x16x32_bf16(afr[kt].h, bF.h, acc, 0,0,0);
          }
          if (qq==0){
            int j = nt*16+cc;
            *(float*)(smem + OFF_X + bl*XSTR + j*4) += acc[0] + p.bo[li*128+j];
          }
        }
      }
      __syncthreads();
    }

    ln_to_xh(smem, tid);
    __syncthreads();
    {
      FragU afr[4];
      #pragma unroll
      for (int kt=0;kt<4;++kt) afr[kt].u = *(const uint4*)(smem+OFF_XH + cc*XHSTR + kt*64 + qq*16);
      const ushort* W = g_W1T + li*65536;
      ushort* H = (ushort*)(smem+OFF_H1);
      #pragma unroll
      for (int i=0;i<8;++i){
        int nt = w*8+i;
        f32x4 acc={0.f,0.f,0.f,0.f};
        #pragma unroll
        for (int kt=0;kt<4;++kt){
          FragU bF; bF.u = *(const uint4*)(W + (nt*16+cc)*128 + kt*32 + qq*8);
          acc = __builtin_amdgcn_mfma_f32_16x16x32_bf16(afr[kt].h, bF.h, acc, 0,0,0);
        }
        int col = nt*16+cc;
        float bv = bf2f(g_b1F[li*512+col]);
        #pragma unroll
        for (int r=0;r<4;++r){
          float v = acc[r]+bv;
          v = 0.5f*v*(1.f+erff(v*0.70710678118654752f));
          H[(qq*4+r)*520 + col] = f2bf(v);
        }
      }
    }
    __syncthreads();
    {
      const ushort* W = g_W2T + li*65536;
      #pragma unroll
      for (int i=0;i<2;++i){
        int nt = w*2+i;
        f32x4 acc={0.f,0.f,0.f,0.f};
        #pragma unroll
        for (int kt=0;kt<16;++kt){
          FragU a,bF;
          a.u = *(const uint4*)(smem+OFF_H1 + cc*1040 + kt*64 + qq*16);
          bF.u = *(const uint4*)(W + (nt*16+cc)*512 + kt*32 + qq*8);
          acc = __builtin_amdgcn_mfma_f32_16x16x32_bf16(a.h, bF.h, acc, 0,0,0);
        }
        int col = nt*16+cc;
        float bv = p.b2[li*128+col];
        #pragma unroll
        for (int r=0;r<4;++r){
          float* xp = (float*)(smem+OFF_X+(qq*4+r)*XSTR+col*4);
          *xp += acc[r]+bv;
        }
      }
    }
    __syncthreads();
  }

  cvt_x_to_xh(smem, tid);
  __syncthreads();
  {
    #pragma unroll
    for (int i=0;i<2;++i){
      int nt = w*2+i;
      f32x4 acc = {0.f,0.f,0.f,0.f};
      #pragma unroll
      for (int kt=0;kt<4;++kt){
        FragU a,bF;
        a.u = *(const uint4*)(smem + OFF_XH + cc*XHSTR + kt*64 + qq*16);
        bF.u = *(const uint4*)(g_outT + (nt*16+cc)*128 + kt*32 + qq*8);
        acc = __builtin_amdgcn_mfma_f32_16x16x32_bf16(a.h, bF.h, acc, 0,0,0);
      }
      int col = nt*16+cc;
      float bv = p.out_b[col];
      #pragma unroll
      for (int r=0;r<4;++r) *(float*)(smem+OFF_X+(qq*4+r)*XSTR+col*4) = acc[r]+bv;
    }
  }
  __syncthreads();
  {
    int b_=tid>>4, pp=tid&15;
    const char* xr = smem + OFF_X + b_*XSTR + pp*32;
    float v[8];
    #pragma unroll
    for (int i=0;i<4;++i){ float2 t2 = *(const float2*)(xr + i*8); v[2*i]=t2.x; v[2*i+1]=t2.y; }
    float s1=0.f, s2=0.f;
    #pragma unroll
    for (int i=0;i<8;++i){ s1+=v[i]; s2+=v[i]*v[i]; }
    for (int o=1;o<16;o<<=1){ s1 += __shfl_xor(s1,o); s2 += __shfl_xor(s2,o); }
    float m = s1*0.0078125f, rs = rsqrtf(s2*0.0078125f - m*m + 1e-5f);
    float4 o0,o1;
    o0.x=(v[0]-m)*rs*p.out_g[pp*8+0]+p.out_bb[pp*8+0];
    o0.y=(v[1]-m)*rs*p.out_g[pp*8+1]+p.out_bb[pp*8+1];
    o0.z=(v[2]-m)*rs*p.out_g[pp*8+2]+p.out_bb[pp*8+2];
    o0.w=(v[3]-m)*rs*p.out_g[pp*8+3]+p.out_bb[pp*8+3];
    o1.x=(v[4]-m)*rs*p.out_g[pp*8+4]+p.out_bb[pp*8+4];
    o1.y=(v[5]-m)*rs*p.out_g[pp*8+5]+p.out_bb[pp*8+5];
    o1.z=(v[6]-m)*rs*p.out_g[pp*8+6]+p.out_bb[pp*8+6];
    o1.w=(v[7]-m)*rs*p.out_g[pp*8+7]+p.out_bb[pp*8+7];
    float* dst = p.outp + (size_t)(bB+b_)*128 + pp*8;
    *(float4*)dst = o0; *(float4*)(dst+4) = o1;
  }
}

// ---------------- host ----------------
extern "C" void kernel_launch(void* const* d_in, const int* in_sizes, int n_in,
                              void* d_out, int out_size, void* d_ws, size_t ws_size,
                              hipStream_t stream){
  (void)in_sizes; (void)n_in; (void)out_size;
  char* ws = (char*)d_ws;
  const size_t NEED1 = (size_t)B_*16384;   // dense nbg: 128 MiB

  P p;
  p.ego=(const float*)d_in[0]; p.epos=(const float*)d_in[1]; p.evel=(const float*)d_in[2];
  p.npos=(const float*)d_in[3]; p.nvel=(const float*)d_in[4]; p.mask=(const int*)d_in[5];
  p.npW=(const float*)d_in[6]; p.npb=(const float*)d_in[7]; p.npg=(const float*)d_in[8]; p.npbb=(const float*)d_in[9];
  p.ego_b=(const float*)d_in[11]; p.ego_g=(const float*)d_in[12]; p.ego_bb=(const float*)d_in[13];
  p.bo=(const float*)d_in[27]; p.b2=(const float*)d_in[31];
  p.out_b=(const float*)d_in[33]; p.out_g=(const float*)d_in[34]; p.out_bb=(const float*)d_in[35];
  p.nbg = (ushort*)ws;
  p.outp=(float*)d_out;

  prep_all<<<3713, 256, 0, stream>>>(p,
      (const float*)d_in[20],(const float*)d_in[21],(const float*)d_in[14],(const float*)d_in[15],
      (const float*)d_in[22],(const float*)d_in[23],(const float*)d_in[16],(const float*)d_in[17],
      (const float*)d_in[24],(const float*)d_in[25],
      (const float*)d_in[28],(const float*)d_in[29],(const float*)d_in[18],(const float*)d_in[19],
      (const float*)d_in[26],(const float*)d_in[30],(const float*)d_in[10],(const float*)d_in[32]);

  if (ws_size >= NEED1){
    st_main7<<<B_/16,256,0,stream>>>(p);
  } else {
    st_main0<<<B_/16,256,0,stream>>>(p);
  }
}

// Round 12
// 606.338 us; speedup vs baseline: 1.2699x; 1.2699x over previous
//
#include <hip/hip_runtime.h>
#include <stdint.h>

typedef unsigned int uint;
typedef unsigned short ushort;
typedef unsigned long long u64;

#define B_   8192
#define D_   128
#define N_   64
#define L_   3

typedef __attribute__((ext_vector_type(8))) short short8;
typedef __attribute__((ext_vector_type(4))) float f32x4;
union FragU { uint4 u; short8 h; };

__device__ __forceinline__ float bf2f(ushort u){ union{uint i; float f;} c; c.i=((uint)u)<<16; return c.f; }
__device__ __forceinline__ float bflo(uint u){ union{uint i; float f;} c; c.i=u<<16; return c.f; }
__device__ __forceinline__ float bfhi(uint u){ union{uint i; float f;} c; c.i=u&0xffff0000u; return c.f; }
__device__ __forceinline__ ushort f2bf(float f){ uint u=__float_as_uint(f); return (ushort)((u + 0x7fffu + ((u>>16)&1u))>>16); }
__device__ __forceinline__ uint pk2(float lo, float hi){ return (uint)f2bf(lo) | (((uint)f2bf(hi))<<16); }
__device__ __forceinline__ float wsum(float v){ for (int o=32;o;o>>=1) v += __shfl_xor(v,o); return v; }

// ---------------- static device storage for folded weights ----------------
__device__ ushort g_WqT[3*128*128];
__device__ ushort g_WkT[3*128*128];
__device__ ushort g_WvT[3*128*128];
__device__ ushort g_WoT[3*128*128];
__device__ ushort g_W1T[3*512*128];
__device__ ushort g_W2T[3*128*512];
__device__ ushort g_egoT[128*128];
__device__ ushort g_outT[128*128];
__device__ float  g_npRec[128*9];
__device__ ushort g_bqF[384];
__device__ ushort g_bkF[384];
__device__ ushort g_bvF[384];
__device__ ushort g_b1F[1536];
__device__ u64    g_msk[B_];

// ---------------- LDS layout (bytes) ----------------
#define OFF_X   0        // x residual: f32 [16][130]  (stride 520 B)
#define XSTR    520
#define OFF_XH  8320     // A operand bf16 [16][136]   (stride 272 B)
#define XHSTR   272
#define OFF_Q   12672    // Q bf16 [16][130] (stride 260 B)
#define QSTR    260
#define OFF_QK  16832    // qk bf16 [16][136] (rows 8..15 zeroed once)
#define QKSTR   272
#define OFF_QB  21184    // qb f32 [16] (rows 8..15 zero)
#define OFF_V   21248    // valid flags f32 [64]
#define OFF_NB  21504    // nbhat n-major bf16 [64][136]
#define NBSTR   272
#define OFF_NT  38912    // nbhat d-major bf16 [128][72]
#define NTSTR   144
#define OFF_AT  57344    // attn bf16 [16][72]
#define ATSTR   144
#define OFF_U   59648    // U bf16 [8][136] (stride 272; rows=h, cols=d)
#define USTR    272
#define OFF_CXH 61824    // ctx bf16 [128] (256 B)
#define OFF_H1  21504    // h1 bf16 [16][520] — aliases NB region (FFN phase only)
#define LDS_SZ  62272

struct P {
  const float *ego, *epos, *evel, *npos, *nvel;
  const int   *mask;
  const float *npW, *npb, *npg, *npbb;
  const float *ego_b, *ego_g, *ego_bb;
  const float *bo, *b2, *out_b, *out_g, *out_bb;
  ushort *nbg;           // dense nbhat n-major, 16 KB per batch
  float *outp;
};

// ---------------- prep_all: weight fold/transpose + npRec + nbhat + msk ----------------
// grid roles: [0,2688) prepF, [2688,3712) prepP, 3712 prepNp, [3713, 3713+B_/2) nb staging (2 batches/block)
template<int MODE>  // MODE1: with nb staging; MODE0: weights only
__global__ __launch_bounds__(256,4) void prep_all(P p,
    const float* Wq,const float* bq,const float* n1g,const float* n1b,
    const float* Wk,const float* bk,const float* nkg,const float* nkb,
    const float* Wv,const float* bv,
    const float* W1,const float* b1,const float* n2g,const float* n2b,
    const float* Wo,const float* W2,const float* egoW,const float* outW){
  __shared__ float red[2];
  __shared__ float s_npW[768], s_npP[384];
  __shared__ float s_valid[2][64];
  const int bid = blockIdx.x;
  const int tid = threadIdx.x;
  if (bid < 2688){
    int t = tid;
    const float *src,*g,*bb,*bias; ushort *dstW,*dstB; int N;
    if (bid<384){ int l=bid>>7, j=bid&127; src=Wq+l*16384+j; g=n1g+l*128; bb=n1b+l*128; bias=bq+l*128+j; dstW=g_WqT+l*16384+j*128; dstB=g_bqF+l*128+j; N=128; }
    else if (bid<768){ int q=bid-384; int l=q>>7, j=q&127; src=Wk+l*16384+j; g=nkg+l*128; bb=nkb+l*128; bias=bk+l*128+j; dstW=g_WkT+l*16384+j*128; dstB=g_bkF+l*128+j; N=128; }
    else if (bid<1152){ int q=bid-768; int l=q>>7, j=q&127; src=Wv+l*16384+j; g=nkg+l*128; bb=nkb+l*128; bias=bv+l*128+j; dstW=g_WvT+l*16384+j*128; dstB=g_bvF+l*128+j; N=128; }
    else { int q=bid-1152; int l=q/512, j=q%512; src=W1+l*65536+j; g=n2g+l*128; bb=n2b+l*128; bias=b1+l*512+j; dstW=g_W1T+l*65536+j*128; dstB=g_b1F+l*512+j; N=512; }
    if (t<128){
      float wv = src[t*N];
      dstW[t] = f2bf(g[t]*wv);
      float pv = wsum(bb[t]*wv);
      if ((t&63)==0) red[t>>6]=pv;
    }
    __syncthreads();
    if (t==0) *dstB = f2bf(red[0]+red[1]+bias[0]);
  } else if (bid < 3712){
    int pb = bid - 2688, t = tid;
    if (t<128){
      if (pb<384){ int l=pb>>7, j=pb&127; g_WoT[l*16384+j*128+t] = f2bf(Wo[l*16384+t*128+j]); }
      else if (pb<768){ int q=pb-384; int l=q>>7, j=q&127;
        for (int k=t;k<512;k+=128) g_W2T[l*65536+j*512+k] = f2bf(W2[l*65536+k*128+j]); }
      else if (pb<896){ int j=pb-768; g_egoT[j*128+t]=f2bf(egoW[t*128+j]); }
      else { int j=pb-896; g_outT[j*128+t]=f2bf(outW[t*128+j]); }
    }
  } else if (bid == 3712){
    int t = tid;
    if (t<128){
      for (int r=0;r<6;++r) g_npRec[t*9+r]=p.npW[r*128+t];
      g_npRec[t*9+6]=p.npb[t]; g_npRec[t*9+7]=p.npg[t]; g_npRec[t*9+8]=p.npbb[t];
    }
  } else {
    // nb staging (r1-lineage st_nb, verified): 2 batches/block, dense nbg + g_msk
    const int bq2 = bid - 3713;
    const int g = tid>>7, t = tid&127;
    const int b = bq2*2+g;
    for (int i=tid;i<768;i+=256) s_npW[i]=p.npW[i];
    if (tid<128){ s_npP[tid]=p.npb[tid]; s_npP[128+tid]=p.npg[tid]; s_npP[256+tid]=p.npbb[tid]; }
    __syncthreads();
    int nn=t>>1, jh=t&1;
    float2 pn = ((const float2*)p.npos)[b*N_+nn];
    float2 vn = ((const float2*)p.nvel)[b*N_+nn];
    float2 pe = ((const float2*)p.epos)[b];
    float2 ve = ((const float2*)p.evel)[b];
    float rx=pn.x-pe.x, ry=pn.y-pe.y, rvx=vn.x-ve.x, rvy=vn.y-ve.y;
    float nrm = sqrtf(rx*rx+ry*ry);
    float dist = fmaxf(nrm,1e-6f), bear = atan2f(ry+1e-8f, rx+1e-8f);
    bool vld = (p.mask[b*N_+nn]!=0) && (nrm<3.0f);
    if (jh==0) s_valid[g][nn] = vld?1.f:0.f;
    float z[64]; float sa=0.f, sb=0.f;
    #pragma unroll
    for (int jj=0;jj<64;++jj){
      int j = jh*64+jj;
      float v = s_npP[j] + rx*s_npW[j] + ry*s_npW[128+j] + rvx*s_npW[256+j]
                         + rvy*s_npW[384+j] + dist*s_npW[512+j] + bear*s_npW[640+j];
      z[jj]=v; sa+=v; sb+=v*v;
    }
    sa += __shfl_xor(sa,1); sb += __shfl_xor(sb,1);
    float m1 = sa*0.0078125f, r1 = rsqrtf(sb*0.0078125f - m1*m1 + 1e-5f);
    float ta=0.f, tb=0.f;
    #pragma unroll
    for (int jj=0;jj<64;++jj){
      int j = jh*64+jj;
      float a = (z[jj]-m1)*r1*s_npP[128+j] + s_npP[256+j];
      a = fmaxf(a,0.f);
      z[jj]=a; ta+=a; tb+=a*a;
    }
    ta += __shfl_xor(ta,1); tb += __shfl_xor(tb,1);
    float m2 = ta*0.0078125f, r2 = rsqrtf(tb*0.0078125f - m2*m2 + 1e-5f);
    // thread t owns a contiguous 128B run (nn*256 + jh*128 == t*128) of the 16KB batch slot
    uint4* dst4 = (uint4*)((char*)p.nbg + (size_t)b*16384 + (size_t)t*128);
    #pragma unroll
    for (int q8=0;q8<8;++q8){
      uint prs[4];
      #pragma unroll
      for (int qi=0;qi<4;++qi){
        int q = q8*4+qi;
        prs[qi] = pk2((z[2*q]-m2)*r2, (z[2*q+1]-m2)*r2);
      }
      uint4 ov; ov.x=prs[0]; ov.y=prs[1]; ov.z=prs[2]; ov.w=prs[3];
      dst4[q8] = ov;
    }
    __syncthreads();
    if (tid<2){
      u64 m=0;
      for (int n=0;n<64;++n) if (s_valid[tid][n]>0.5f) m |= (1ULL<<n);
      g_msk[bq2*2+tid] = m;
    }
  }
}

// ---------------- shared helpers ----------------
__device__ __forceinline__ void ln_to_xh(char* smem, int tid){
  int b = tid>>4, pp = tid&15;
  const char* xr = smem + OFF_X + b*XSTR + pp*32;
  float v[8];
  #pragma unroll
  for (int i=0;i<4;++i){ float2 t2 = *(const float2*)(xr + i*8); v[2*i]=t2.x; v[2*i+1]=t2.y; }
  float s1=0.f, s2=0.f;
  #pragma unroll
  for (int i=0;i<8;++i){ s1+=v[i]; s2+=v[i]*v[i]; }
  for (int o=1;o<16;o<<=1){ s1 += __shfl_xor(s1,o); s2 += __shfl_xor(s2,o); }
  float m = s1*0.0078125f, rs = rsqrtf(s2*0.0078125f - m*m + 1e-5f);
  uint4 o4;
  o4.x = pk2((v[0]-m)*rs,(v[1]-m)*rs); o4.y = pk2((v[2]-m)*rs,(v[3]-m)*rs);
  o4.z = pk2((v[4]-m)*rs,(v[5]-m)*rs); o4.w = pk2((v[6]-m)*rs,(v[7]-m)*rs);
  *(uint4*)(smem + OFF_XH + b*XHSTR + pp*16) = o4;
}

__device__ __forceinline__ void ln_affine_inplace(char* smem, int tid, const float* g, const float* bb){
  int b = tid>>4, pp = tid&15;
  char* xr = smem + OFF_X + b*XSTR + pp*32;
  float v[8];
  #pragma unroll
  for (int i=0;i<4;++i){ float2 t2 = *(const float2*)(xr + i*8); v[2*i]=t2.x; v[2*i+1]=t2.y; }
  float s1=0.f, s2=0.f;
  #pragma unroll
  for (int i=0;i<8;++i){ s1+=v[i]; s2+=v[i]*v[i]; }
  for (int o=1;o<16;o<<=1){ s1 += __shfl_xor(s1,o); s2 += __shfl_xor(s2,o); }
  float m = s1*0.0078125f, rs = rsqrtf(s2*0.0078125f - m*m + 1e-5f);
  #pragma unroll
  for (int i=0;i<8;++i) v[i] = (v[i]-m)*rs*g[pp*8+i] + bb[pp*8+i];
  #pragma unroll
  for (int i=0;i<4;++i){ float2 t2; t2.x=v[2*i]; t2.y=v[2*i+1]; *(float2*)(xr + i*8) = t2; }
}

__device__ __forceinline__ void cvt_x_to_xh(char* smem, int tid){
  int b = tid>>4, pp = tid&15;
  const char* xr = smem + OFF_X + b*XSTR + pp*32;
  float v[8];
  #pragma unroll
  for (int i=0;i<4;++i){ float2 t2 = *(const float2*)(xr + i*8); v[2*i]=t2.x; v[2*i+1]=t2.y; }
  uint4 o4;
  o4.x=pk2(v[0],v[1]); o4.y=pk2(v[2],v[3]); o4.z=pk2(v[4],v[5]); o4.w=pk2(v[6],v[7]);
  *(uint4*)(smem + OFF_XH + b*XHSTR + pp*16) = o4;
}

// ================= st_main6: r8-verified structure + MFMA-ized ctx/Wo epilogue =================
__global__ __launch_bounds__(256,2) void st_main6(P p){
  __shared__ __align__(16) char smem[LDS_SZ];
  const int tid = threadIdx.x;
  const int w = tid>>6, l64 = tid&63;
  const int cc = l64&15, qq = l64>>4;
  const int bB = blockIdx.x*16;

  // one-time zeroing: qk rows (all; 8..15 stay 0), qb, attn rows 8..15
  for (int i=tid;i<1088;i+=256) ((uint*)(smem+OFF_QK))[i]=0u;
  if (tid<16) ((float*)(smem+OFF_QB))[tid]=0.f;
  for (int i=tid;i<288;i+=256) ((uint*)(smem+OFF_AT+8*ATSTR))[i]=0u;

  // ego: cvt input -> xh
  {
    int b_=tid>>4, pp=tid&15;
    const float* src = p.ego + (size_t)(bB+b_)*128 + pp*8;
    float4 v0 = *(const float4*)src, v1 = *(const float4*)(src+4);
    uint4 o4; o4.x=pk2(v0.x,v0.y); o4.y=pk2(v0.z,v0.w); o4.z=pk2(v1.x,v1.y); o4.w=pk2(v1.z,v1.w);
    *(uint4*)(smem + OFF_XH + b_*XHSTR + pp*16) = o4;
  }
  __syncthreads();
  // ego GEMM -> x (f32, +ego_b)
  {
    #pragma unroll
    for (int i=0;i<2;++i){
      int nt = w*2+i;
      f32x4 acc = {0.f,0.f,0.f,0.f};
      #pragma unroll
      for (int kt=0;kt<4;++kt){
        FragU a,bF;
        a.u = *(const uint4*)(smem + OFF_XH + cc*XHSTR + kt*64 + qq*16);
        bF.u = *(const uint4*)(g_egoT + (nt*16+cc)*128 + kt*32 + qq*8);
        acc = __builtin_amdgcn_mfma_f32_16x16x32_bf16(a.h, bF.h, acc, 0,0,0);
      }
      int col = nt*16+cc;
      float bv = p.ego_b[col];
      #pragma unroll
      for (int r=0;r<4;++r) *(float*)(smem+OFF_X+(qq*4+r)*XSTR+col*4) = acc[r]+bv;
    }
  }
  __syncthreads();
  ln_affine_inplace(smem, tid, p.ego_g, p.ego_bb);
  __syncthreads();

  for (int li=0; li<L_; ++li){
    // LN(x) -> xh (n1 folded)
    ln_to_xh(smem, tid);
    __syncthreads();
    // Q GEMM
    {
      const ushort* W = g_WqT + li*16384;
      #pragma unroll
      for (int i=0;i<2;++i){
        int nt = w*2+i;
        f32x4 acc = {0.f,0.f,0.f,0.f};
        #pragma unroll
        for (int kt=0;kt<4;++kt){
          FragU a,bF;
          a.u = *(const uint4*)(smem + OFF_XH + cc*XHSTR + kt*64 + qq*16);
          bF.u = *(const uint4*)(W + (nt*16+cc)*128 + kt*32 + qq*8);
          acc = __builtin_amdgcn_mfma_f32_16x16x32_bf16(a.h, bF.h, acc, 0,0,0);
        }
        int col = nt*16+cc;
        float bv = bf2f(g_bqF[li*128+col]);
        ushort* Qm = (ushort*)(smem+OFF_Q);
        #pragma unroll
        for (int r=0;r<4;++r) Qm[(qq*4+r)*130 + col] = f2bf(acc[r]+bv);
      }
    }
    __syncthreads();

    // ---- attention rounds: 1 batch per round, 4 waves cooperate ----
    for (int bl=0; bl<16; ++bl){
      const int b = bB + bl;
      // stage nbhat (both layouts) + valid
      {
        int n = w*16 + (l64>>2), seg = l64&3;
        if (seg==0){
          u64 mv = g_msk[b];
          *(float*)(smem+OFF_V+n*4) = ((mv>>n)&1ULL) ? 1.f : 0.f;
        }
        const uint4* src = (const uint4*)(p.nbg + (size_t)b*8192 + n*128);
        ushort* T = (ushort*)(smem+OFF_NT);
        #pragma unroll
        for (int i=0;i<4;++i){
          int ci = seg + i*4;
          uint4 v = src[ci];
          *(uint4*)(smem + OFF_NB + n*NBSTR + ci*16) = v;
          int d0 = ci*8;
          T[(d0+0)*72+n]=(ushort)v.x; T[(d0+1)*72+n]=(ushort)(v.x>>16);
          T[(d0+2)*72+n]=(ushort)v.y; T[(d0+3)*72+n]=(ushort)(v.y>>16);
          T[(d0+4)*72+n]=(ushort)v.z; T[(d0+5)*72+n]=(ushort)(v.z>>16);
          T[(d0+6)*72+n]=(ushort)v.w; T[(d0+7)*72+n]=(ushort)(v.w>>16);
        }
      }
      // qk fold: qk[h][d] = sum_j WkT'[h16+j][d] * Q[bl][h16+j]; qb[h]
      {
        int h = (w<<1) + (l64>>5);
        int d4 = (l64&31)*4;
        const ushort* Wk = g_WkT + li*16384;
        float a0=0.f,a1=0.f,a2=0.f,a3=0.f, qb=0.f;
        #pragma unroll
        for (int j=0;j<16;++j){
          float qv = bf2f(*(const ushort*)(smem + OFF_Q + bl*QSTR + (h*16+j)*2));
          uint2 wv = *(const uint2*)(Wk + (h*16+j)*128 + d4);
          a0 += qv*bflo(wv.x); a1 += qv*bfhi(wv.x);
          a2 += qv*bflo(wv.y); a3 += qv*bfhi(wv.y);
          qb += qv * bf2f(g_bkF[li*128 + h*16 + j]);
        }
        uint2 o; o.x = pk2(a0,a1); o.y = pk2(a2,a3);
        *(uint2*)(smem + OFF_QK + h*QKSTR + d4*2) = o;
        if ((l64&31)==0) *(float*)(smem+OFF_QB + h*4) = qb;
      }
      __syncthreads();

      // scores^T = nbhat @ qk^T via MFMA (redundant on 4 waves), softmax
      {
        FragU bfr[4];
        #pragma unroll
        for (int kt=0;kt<4;++kt) bfr[kt].u = *(const uint4*)(smem + OFF_QK + cc*QKSTR + kt*64 + qq*16);
        f32x4 c[4];
        #pragma unroll
        for (int mt=0;mt<4;++mt){
          f32x4 acc = {0.f,0.f,0.f,0.f};
          #pragma unroll
          for (int kt=0;kt<4;++kt){
            FragU a; a.u = *(const uint4*)(smem + OFF_NB + (mt*16+cc)*NBSTR + kt*64 + qq*16);
            acc = __builtin_amdgcn_mfma_f32_16x16x32_bf16(a.h, bfr[kt].h, acc, 0,0,0);
          }
          c[mt]=acc;
        }
        float qbv = *(const float*)(smem+OFF_QB+cc*4);
        float fl[16]; float anyv=0.f;
        #pragma unroll
        for (int mt=0;mt<4;++mt)
          #pragma unroll
          for (int r=0;r<4;++r){
            int n = mt*16 + qq*4 + r;
            float f = *(const float*)(smem+OFF_V+n*4);
            fl[mt*4+r]=f; anyv+=f;
          }
        bool none = (__ballot(anyv>0.5f)==0ULL);
        float sc[16];
        #pragma unroll
        for (int mt=0;mt<4;++mt)
          #pragma unroll
          for (int r=0;r<4;++r){
            int k = mt*4+r; int n = mt*16+qq*4+r;
            bool ok = (fl[k]>0.5f) || (none && n==0);
            sc[k] = ok ? 0.25f*(c[mt][r]+qbv) : -1e9f;
          }
        float mx=-3e38f;
        #pragma unroll
        for (int k=0;k<16;++k) mx=fmaxf(mx,sc[k]);
        mx = fmaxf(mx,__shfl_xor(mx,16)); mx = fmaxf(mx,__shfl_xor(mx,32));
        float ex[16]; float se=0.f;
        #pragma unroll
        for (int k=0;k<16;++k){ ex[k]=__expf(sc[k]-mx); se+=ex[k]; }
        se += __shfl_xor(se,16); se += __shfl_xor(se,32);
        float inv = 1.f/se;
        if (w==0 && cc<8){
          ushort* A = (ushort*)(smem+OFF_AT);
          #pragma unroll
          for (int mt=0;mt<4;++mt)
            #pragma unroll
            for (int r=0;r<4;++r) A[cc*72 + (mt*16+qq*4+r)] = f2bf(ex[mt*4+r]*inv);
        }
      }
      __syncthreads();

      // U = attn @ nbhat via MFMA (B from transposed copy) -> U[h][d] bf16, stride 272
      {
        #pragma unroll
        for (int i=0;i<2;++i){
          int nt = w*2 + i;
          f32x4 acc={0.f,0.f,0.f,0.f};
          #pragma unroll
          for (int kt=0;kt<2;++kt){
            FragU a,bF;
            a.u = *(const uint4*)(smem + OFF_AT + cc*ATSTR + kt*64 + qq*16);
            bF.u = *(const uint4*)(smem + OFF_NT + (nt*16+cc)*NTSTR + kt*64 + qq*16);
            acc = __builtin_amdgcn_mfma_f32_16x16x32_bf16(a.h, bF.h, acc, 0,0,0);
          }
          if (qq<2){
            ushort* U = (ushort*)(smem+OFF_U);
            #pragma unroll
            for (int r=0;r<4;++r) U[(qq*4+r)*136 + nt*16+cc] = f2bf(acc[r]);
          }
        }
      }
      __syncthreads();

      // ctx via MFMA: D[h][j] = sum_d U[h,d]*WvT'[j,d]; extract diag block h = nt
      {
        FragU afr[4];
        #pragma unroll
        for (int kt=0;kt<4;++kt)
          afr[kt].u = *(const uint4*)(smem + OFF_U + (cc&7)*USTR + kt*64 + qq*16);
        #pragma unroll
        for (int i=0;i<2;++i){
          int nt = w*2+i;           // == head h for this column tile
          f32x4 acc={0.f,0.f,0.f,0.f};
          #pragma unroll
          for (int kt=0;kt<4;++kt){
            FragU bF; bF.u = *(const uint4*)(g_WvT + li*16384 + (nt*16+cc)*128 + kt*32 + qq*8);
            acc = __builtin_amdgcn_mfma_f32_16x16x32_bf16(afr[kt].h, bF.h, acc, 0,0,0);
          }
          if (qq == (nt>>2)){
            int j = nt*16+cc;
            ((ushort*)(smem+OFF_CXH))[j] = f2bf(acc[nt&3] + bf2f(g_bvF[li*128+j]));
          }
        }
      }
      __syncthreads();

      // x[bl] += cx @ WoT + bo via MFMA (A broadcast: all lanes read same cxh fragment)
      {
        FragU afr[4];
        #pragma unroll
        for (int kt=0;kt<4;++kt)
          afr[kt].u = *(const uint4*)(smem + OFF_CXH + kt*64 + qq*16);
        #pragma unroll
        for (int i=0;i<2;++i){
          int nt = w*2+i;
          f32x4 acc={0.f,0.f,0.f,0.f};
          #pragma unroll
          for (int kt=0;kt<4;++kt){
            FragU bF; bF.u = *(const uint4*)(g_WoT + li*16384 + (nt*16+cc)*128 + kt*32 + qq*8);
            acc = __builtin_amdgcn_mfma_f32_16x16x32_bf16(afr[kt].h, bF.h, acc, 0,0,0);
          }
          if (qq==0){
            int j = nt*16+cc;
            *(float*)(smem + OFF_X + bl*XSTR + j*4) += acc[0] + p.bo[li*128+j];
          }
        }
      }
      __syncthreads();
    } // rounds

    // FFN: LN(x) -> xh (n2 folded)
    ln_to_xh(smem, tid);
    __syncthreads();
    // W1 GEMM + gelu -> h1
    {
      FragU afr[4];
      #pragma unroll
      for (int kt=0;kt<4;++kt) afr[kt].u = *(const uint4*)(smem+OFF_XH + cc*XHSTR + kt*64 + qq*16);
      const ushort* W = g_W1T + li*65536;
      ushort* H = (ushort*)(smem+OFF_H1);
      #pragma unroll
      for (int i=0;i<8;++i){
        int nt = w*8+i;
        f32x4 acc={0.f,0.f,0.f,0.f};
        #pragma unroll
        for (int kt=0;kt<4;++kt){
          FragU bF; bF.u = *(const uint4*)(W + (nt*16+cc)*128 + kt*32 + qq*8);
          acc = __builtin_amdgcn_mfma_f32_16x16x32_bf16(afr[kt].h, bF.h, acc, 0,0,0);
        }
        int col = nt*16+cc;
        float bv = bf2f(g_b1F[li*512+col]);
        #pragma unroll
        for (int r=0;r<4;++r){
          float v = acc[r]+bv;
          v = 0.5f*v*(1.f+erff(v*0.70710678118654752f));
          H[(qq*4+r)*520 + col] = f2bf(v);
        }
      }
    }
    __syncthreads();
    // W2 GEMM -> x +=
    {
      const ushort* W = g_W2T + li*65536;
      #pragma unroll
      for (int i=0;i<2;++i){
        int nt = w*2+i;
        f32x4 acc={0.f,0.f,0.f,0.f};
        #pragma unroll
        for (int kt=0;kt<16;++kt){
          FragU a,bF;
          a.u = *(const uint4*)(smem+OFF_H1 + cc*1040 + kt*64 + qq*16);
          bF.u = *(const uint4*)(W + (nt*16+cc)*512 + kt*32 + qq*8);
          acc = __builtin_amdgcn_mfma_f32_16x16x32_bf16(a.h, bF.h, acc, 0,0,0);
        }
        int col = nt*16+cc;
        float bv = p.b2[li*128+col];
        #pragma unroll
        for (int r=0;r<4;++r){
          float* xp = (float*)(smem+OFF_X+(qq*4+r)*XSTR+col*4);
          *xp += acc[r]+bv;
        }
      }
    }
    __syncthreads();
  } // layers

  // output: LN(x @ outW + out_b)
  cvt_x_to_xh(smem, tid);
  __syncthreads();
  {
    #pragma unroll
    for (int i=0;i<2;++i){
      int nt = w*2+i;
      f32x4 acc = {0.f,0.f,0.f,0.f};
      #pragma unroll
      for (int kt=0;kt<4;++kt){
        FragU a,bF;
        a.u = *(const uint4*)(smem + OFF_XH + cc*XHSTR + kt*64 + qq*16);
        bF.u = *(const uint4*)(g_outT + (nt*16+cc)*128 + kt*32 + qq*8);
        acc = __builtin_amdgcn_mfma_f32_16x16x32_bf16(a.h, bF.h, acc, 0,0,0);
      }
      int col = nt*16+cc;
      float bv = p.out_b[col];
      #pragma unroll
      for (int r=0;r<4;++r) *(float*)(smem+OFF_X+(qq*4+r)*XSTR+col*4) = acc[r]+bv;
    }
  }
  __syncthreads();
  {
    int b_=tid>>4, pp=tid&15;
    const char* xr = smem + OFF_X + b_*XSTR + pp*32;
    float v[8];
    #pragma unroll
    for (int i=0;i<4;++i){ float2 t2 = *(const float2*)(xr + i*8); v[2*i]=t2.x; v[2*i+1]=t2.y; }
    float s1=0.f, s2=0.f;
    #pragma unroll
    for (int i=0;i<8;++i){ s1+=v[i]; s2+=v[i]*v[i]; }
    for (int o=1;o<16;o<<=1){ s1 += __shfl_xor(s1,o); s2 += __shfl_xor(s2,o); }
    float m = s1*0.0078125f, rs = rsqrtf(s2*0.0078125f - m*m + 1e-5f);
    float4 o0,o1;
    o0.x=(v[0]-m)*rs*p.out_g[pp*8+0]+p.out_bb[pp*8+0];
    o0.y=(v[1]-m)*rs*p.out_g[pp*8+1]+p.out_bb[pp*8+1];
    o0.z=(v[2]-m)*rs*p.out_g[pp*8+2]+p.out_bb[pp*8+2];
    o0.w=(v[3]-m)*rs*p.out_g[pp*8+3]+p.out_bb[pp*8+3];
    o1.x=(v[4]-m)*rs*p.out_g[pp*8+4]+p.out_bb[pp*8+4];
    o1.y=(v[5]-m)*rs*p.out_g[pp*8+5]+p.out_bb[pp*8+5];
    o1.z=(v[6]-m)*rs*p.out_g[pp*8+6]+p.out_bb[pp*8+6];
    o1.w=(v[7]-m)*rs*p.out_g[pp*8+7]+p.out_bb[pp*8+7];
    float* dst = p.outp + (size_t)(bB+b_)*128 + pp*8;
    *(float4*)dst = o0; *(float4*)(dst+4) = o1;
  }
}

// ================= fallback main kernel (inline nb compute; small ws) =================
__global__ __launch_bounds__(256,2) void st_main0(P p){
  __shared__ __align__(16) char smem[LDS_SZ];
  const int tid = threadIdx.x;
  const int w = tid>>6, l64 = tid&63;
  const int cc = l64&15, qq = l64>>4;
  const int bB = blockIdx.x*16;

  for (int i=tid;i<1088;i+=256) ((uint*)(smem+OFF_QK))[i]=0u;
  if (tid<16) ((float*)(smem+OFF_QB))[tid]=0.f;
  for (int i=tid;i<288;i+=256) ((uint*)(smem+OFF_AT+8*ATSTR))[i]=0u;

  {
    int b_=tid>>4, pp=tid&15;
    const float* src = p.ego + (size_t)(bB+b_)*128 + pp*8;
    float4 v0 = *(const float4*)src, v1 = *(const float4*)(src+4);
    uint4 o4; o4.x=pk2(v0.x,v0.y); o4.y=pk2(v0.z,v0.w); o4.z=pk2(v1.x,v1.y); o4.w=pk2(v1.z,v1.w);
    *(uint4*)(smem + OFF_XH + b_*XHSTR + pp*16) = o4;
  }
  __syncthreads();
  {
    #pragma unroll
    for (int i=0;i<2;++i){
      int nt = w*2+i;
      f32x4 acc = {0.f,0.f,0.f,0.f};
      #pragma unroll
      for (int kt=0;kt<4;++kt){
        FragU a,bF;
        a.u = *(const uint4*)(smem + OFF_XH + cc*XHSTR + kt*64 + qq*16);
        bF.u = *(const uint4*)(g_egoT + (nt*16+cc)*128 + kt*32 + qq*8);
        acc = __builtin_amdgcn_mfma_f32_16x16x32_bf16(a.h, bF.h, acc, 0,0,0);
      }
      int col = nt*16+cc;
      float bv = p.ego_b[col];
      #pragma unroll
      for (int r=0;r<4;++r) *(float*)(smem+OFF_X+(qq*4+r)*XSTR+col*4) = acc[r]+bv;
    }
  }
  __syncthreads();
  ln_affine_inplace(smem, tid, p.ego_g, p.ego_bb);
  __syncthreads();

  for (int li=0; li<L_; ++li){
    ln_to_xh(smem, tid);
    __syncthreads();
    {
      const ushort* W = g_WqT + li*16384;
      #pragma unroll
      for (int i=0;i<2;++i){
        int nt = w*2+i;
        f32x4 acc = {0.f,0.f,0.f,0.f};
        #pragma unroll
        for (int kt=0;kt<4;++kt){
          FragU a,bF;
          a.u = *(const uint4*)(smem + OFF_XH + cc*XHSTR + kt*64 + qq*16);
          bF.u = *(const uint4*)(W + (nt*16+cc)*128 + kt*32 + qq*8);
          acc = __builtin_amdgcn_mfma_f32_16x16x32_bf16(a.h, bF.h, acc, 0,0,0);
        }
        int col = nt*16+cc;
        float bv = bf2f(g_bqF[li*128+col]);
        ushort* Qm = (ushort*)(smem+OFF_Q);
        #pragma unroll
        for (int r=0;r<4;++r) Qm[(qq*4+r)*130 + col] = f2bf(acc[r]+bv);
      }
    }
    __syncthreads();

    for (int bl=0; bl<16; ++bl){
      const int b = bB + bl;
      {
        int n = w*16 + (l64>>2), jq = l64&3;
        float2 pn = ((const float2*)p.npos)[b*N_+n];
        float2 vn = ((const float2*)p.nvel)[b*N_+n];
        float2 pe = ((const float2*)p.epos)[b];
        float2 ve = ((const float2*)p.evel)[b];
        float rx=pn.x-pe.x, ry=pn.y-pe.y, rvx=vn.x-ve.x, rvy=vn.y-ve.y;
        float nrm = sqrtf(rx*rx+ry*ry);
        float dist = fmaxf(nrm,1e-6f), bear = atan2f(ry+1e-8f, rx+1e-8f);
        if (jq==0){
          bool vld = (p.mask[b*N_+n]!=0) && (nrm<3.0f);
          *(float*)(smem+OFF_V+n*4) = vld?1.f:0.f;
        }
        float z[32]; float sa=0.f, sb=0.f;
        #pragma unroll
        for (int jj=0;jj<32;++jj){
          const float* rec = g_npRec + (jq*32+jj)*9;
          float4 r0 = *(const float4*)rec;
          float4 r1 = *(const float4*)(rec+4);
          float v = r1.z + rx*r0.x + ry*r0.y + rvx*r0.z + rvy*r0.w + dist*r1.x + bear*r1.y;
          z[jj]=v; sa+=v; sb+=v*v;
        }
        sa += __shfl_xor(sa,1); sb += __shfl_xor(sb,1);
        sa += __shfl_xor(sa,2); sb += __shfl_xor(sb,2);
        float m1 = sa*0.0078125f, r1s = rsqrtf(sb*0.0078125f - m1*m1 + 1e-5f);
        float ta=0.f, tb=0.f;
        #pragma unroll
        for (int jj=0;jj<32;++jj){
          const float* rec = g_npRec + (jq*32+jj)*9;
          float a = (z[jj]-m1)*r1s*rec[7] + rec[8];
          a = fmaxf(a,0.f);
          z[jj]=a; ta+=a; tb+=a*a;
        }
        ta += __shfl_xor(ta,1); tb += __shfl_xor(tb,1);
        ta += __shfl_xor(ta,2); tb += __shfl_xor(tb,2);
        float m2 = ta*0.0078125f, r2s = rsqrtf(tb*0.0078125f - m2*m2 + 1e-5f);
        ushort* T = (ushort*)(smem+OFF_NT);
        #pragma unroll
        for (int q2=0;q2<16;++q2){
          uint pr = pk2((z[2*q2]-m2)*r2s, (z[2*q2+1]-m2)*r2s);
          *(uint*)(smem + OFF_NB + n*NBSTR + jq*64 + q2*4) = pr;
          int d = jq*32 + q2*2;
          T[d*72 + n] = (ushort)pr;
          T[(d+1)*72 + n] = (ushort)(pr>>16);
        }
      }
      {
        int h = (w<<1) + (l64>>5);
        int d4 = (l64&31)*4;
        const ushort* Wk = g_WkT + li*16384;
        float a0=0.f,a1=0.f,a2=0.f,a3=0.f, qb=0.f;
        #pragma unroll
        for (int j=0;j<16;++j){
          float qv = bf2f(*(const ushort*)(smem + OFF_Q + bl*QSTR + (h*16+j)*2));
          uint2 wv = *(const uint2*)(Wk + (h*16+j)*128 + d4);
          a0 += qv*bflo(wv.x); a1 += qv*bfhi(wv.x);
          a2 += qv*bflo(wv.y); a3 += qv*bfhi(wv.y);
          qb += qv * bf2f(g_bkF[li*128 + h*16 + j]);
        }
        uint2 o; o.x = pk2(a0,a1); o.y = pk2(a2,a3);
        *(uint2*)(smem + OFF_QK + h*QKSTR + d4*2) = o;
        if ((l64&31)==0) *(float*)(smem+OFF_QB + h*4) = qb;
      }
      __syncthreads();

      {
        FragU bfr[4];
        #pragma unroll
        for (int kt=0;kt<4;++kt) bfr[kt].u = *(const uint4*)(smem + OFF_QK + cc*QKSTR + kt*64 + qq*16);
        f32x4 c[4];
        #pragma unroll
        for (int mt=0;mt<4;++mt){
          f32x4 acc = {0.f,0.f,0.f,0.f};
          #pragma unroll
          for (int kt=0;kt<4;++kt){
            FragU a; a.u = *(const uint4*)(smem + OFF_NB + (mt*16+cc)*NBSTR + kt*64 + qq*16);
            acc = __builtin_amdgcn_mfma_f32_16x16x32_bf16(a.h, bfr[kt].h, acc, 0,0,0);
          }
          c[mt]=acc;
        }
        float qbv = *(const float*)(smem+OFF_QB+cc*4);
        float fl[16]; float anyv=0.f;
        #pragma unroll
        for (int mt=0;mt<4;++mt)
          #pragma unroll
          for (int r=0;r<4;++r){
            int n = mt*16 + qq*4 + r;
            float f = *(const float*)(smem+OFF_V+n*4);
            fl[mt*4+r]=f; anyv+=f;
          }
        bool none = (__ballot(anyv>0.5f)==0ULL);
        float sc[16];
        #pragma unroll
        for (int mt=0;mt<4;++mt)
          #pragma unroll
          for (int r=0;r<4;++r){
            int k = mt*4+r; int n = mt*16+qq*4+r;
            bool ok = (fl[k]>0.5f) || (none && n==0);
            sc[k] = ok ? 0.25f*(c[mt][r]+qbv) : -1e9f;
          }
        float mx=-3e38f;
        #pragma unroll
        for (int k=0;k<16;++k) mx=fmaxf(mx,sc[k]);
        mx = fmaxf(mx,__shfl_xor(mx,16)); mx = fmaxf(mx,__shfl_xor(mx,32));
        float ex[16]; float se=0.f;
        #pragma unroll
        for (int k=0;k<16;++k){ ex[k]=__expf(sc[k]-mx); se+=ex[k]; }
        se += __shfl_xor(se,16); se += __shfl_xor(se,32);
        float inv = 1.f/se;
        if (w==0 && cc<8){
          ushort* A = (ushort*)(smem+OFF_AT);
          #pragma unroll
          for (int mt=0;mt<4;++mt)
            #pragma unroll
            for (int r=0;r<4;++r) A[cc*72 + (mt*16+qq*4+r)] = f2bf(ex[mt*4+r]*inv);
        }
      }
      __syncthreads();

      {
        #pragma unroll
        for (int i=0;i<2;++i){
          int nt = w*2 + i;
          f32x4 acc={0.f,0.f,0.f,0.f};
          #pragma unroll
          for (int kt=0;kt<2;++kt){
            FragU a,bF;
            a.u = *(const uint4*)(smem + OFF_AT + cc*ATSTR + kt*64 + qq*16);
            bF.u = *(const uint4*)(smem + OFF_NT + (nt*16+cc)*NTSTR + kt*64 + qq*16);
            acc = __builtin_amdgcn_mfma_f32_16x16x32_bf16(a.h, bF.h, acc, 0,0,0);
          }
          if (qq<2){
            ushort* U = (ushort*)(smem+OFF_U);
            #pragma unroll
            for (int r=0;r<4;++r) U[(qq*4+r)*136 + nt*16+cc] = f2bf(acc[r]);
          }
        }
      }
      __syncthreads();

      {
        FragU afr[4];
        #pragma unroll
        for (int kt=0;kt<4;++kt)
          afr[kt].u = *(const uint4*)(smem + OFF_U + (cc&7)*USTR + kt*64 + qq*16);
        #pragma unroll
        for (int i=0;i<2;++i){
          int nt = w*2+i;
          f32x4 acc={0.f,0.f,0.f,0.f};
          #pragma unroll
          for (int kt=0;kt<4;++kt){
            FragU bF; bF.u = *(const uint4*)(g_WvT + li*16384 + (nt*16+cc)*128 + kt*32 + qq*8);
            acc = __builtin_amdgcn_mfma_f32_16x16x32_bf16(afr[kt].h, bF.h, acc, 0,0,0);
          }
          if (qq == (nt>>2)){
            int j = nt*16+cc;
            ((ushort*)(smem+OFF_CXH))[j] = f2bf(acc[nt&3] + bf2f(g_bvF[li*128+j]));
          }
        }
      }
      __syncthreads();

      {
        FragU afr[4];
        #pragma unroll
        for (int kt=0;kt<4;++kt)
          afr[kt].u = *(const uint4*)(smem + OFF_CXH + kt*64 + qq*16);
        #pragma unroll
        for (int i=0;i<2;++i){
          int nt = w*2+i;
          f32x4 acc={0.f,0.f,0.f,0.f};
          #pragma unroll
          for (int kt=0;kt<4;++kt){
            FragU bF; bF.u = *(const uint4*)(g_WoT + li*16384 + (nt*16+cc)*128 + kt*32 + qq*8);
            acc = __builtin_amdgcn_mfma_f32_16x16x32_bf16(afr[kt].h, bF.h, acc, 0,0,0);
          }
          if (qq==0){
            int j = nt*16+cc;
            *(float*)(smem + OFF_X + bl*XSTR + j*4) += acc[0] + p.bo[li*128+j];
          }
        }
      }
      __syncthreads();
    }

    ln_to_xh(smem, tid);
    __syncthreads();
    {
      FragU afr[4];
      #pragma unroll
      for (int kt=0;kt<4;++kt) afr[kt].u = *(const uint4*)(smem+OFF_XH + cc*XHSTR + kt*64 + qq*16);
      const ushort* W = g_W1T + li*65536;
      ushort* H = (ushort*)(smem+OFF_H1);
      #pragma unroll
      for (int i=0;i<8;++i){
        int nt = w*8+i;
        f32x4 acc={0.f,0.f,0.f,0.f};
        #pragma unroll
        for (int kt=0;kt<4;++kt){
          FragU bF; bF.u = *(const uint4*)(W + (nt*16+cc)*128 + kt*32 + qq*8);
          acc = __builtin_amdgcn_mfma_f32_16x16x32_bf16(afr[kt].h, bF.h, acc, 0,0,0);
        }
        int col = nt*16+cc;
        float bv = bf2f(g_b1F[li*512+col]);
        #pragma unroll
        for (int r=0;r<4;++r){
          float v = acc[r]+bv;
          v = 0.5f*v*(1.f+erff(v*0.70710678118654752f));
          H[(qq*4+r)*520 + col] = f2bf(v);
        }
      }
    }
    __syncthreads();
    {
      const ushort* W = g_W2T + li*65536;
      #pragma unroll
      for (int i=0;i<2;++i){
        int nt = w*2+i;
        f32x4 acc={0.f,0.f,0.f,0.f};
        #pragma unroll
        for (int kt=0;kt<16;++kt){
          FragU a,bF;
          a.u = *(const uint4*)(smem+OFF_H1 + cc*1040 + kt*64 + qq*16);
          bF.u = *(const uint4*)(W + (nt*16+cc)*512 + kt*32 + qq*8);
          acc = __builtin_amdgcn_mfma_f32_16x16x32_bf16(a.h, bF.h, acc, 0,0,0);
        }
        int col = nt*16+cc;
        float bv = p.b2[li*128+col];
        #pragma unroll
        for (int r=0;r<4;++r){
          float* xp = (float*)(smem+OFF_X+(qq*4+r)*XSTR+col*4);
          *xp += acc[r]+bv;
        }
      }
    }
    __syncthreads();
  }

  cvt_x_to_xh(smem, tid);
  __syncthreads();
  {
    #pragma unroll
    for (int i=0;i<2;++i){
      int nt = w*2+i;
      f32x4 acc = {0.f,0.f,0.f,0.f};
      #pragma unroll
      for (int kt=0;kt<4;++kt){
        FragU a,bF;
        a.u = *(const uint4*)(smem + OFF_XH + cc*XHSTR + kt*64 + qq*16);
        bF.u = *(const uint4*)(g_outT + (nt*16+cc)*128 + kt*32 + qq*8);
        acc = __builtin_amdgcn_mfma_f32_16x16x32_bf16(a.h, bF.h, acc, 0,0,0);
      }
      int col = nt*16+cc;
      float bv = p.out_b[col];
      #pragma unroll
      for (int r=0;r<4;++r) *(float*)(smem+OFF_X+(qq*4+r)*XSTR+col*4) = acc[r]+bv;
    }
  }
  __syncthreads();
  {
    int b_=tid>>4, pp=tid&15;
    const char* xr = smem + OFF_X + b_*XSTR + pp*32;
    float v[8];
    #pragma unroll
    for (int i=0;i<4;++i){ float2 t2 = *(const float2*)(xr + i*8); v[2*i]=t2.x; v[2*i+1]=t2.y; }
    float s1=0.f, s2=0.f;
    #pragma unroll
    for (int i=0;i<8;++i){ s1+=v[i]; s2+=v[i]*v[i]; }
    for (int o=1;o<16;o<<=1){ s1 += __shfl_xor(s1,o); s2 += __shfl_xor(s2,o); }
    float m = s1*0.0078125f, rs = rsqrtf(s2*0.0078125f - m*m + 1e-5f);
    float4 o0,o1;
    o0.x=(v[0]-m)*rs*p.out_g[pp*8+0]+p.out_bb[pp*8+0];
    o0.y=(v[1]-m)*rs*p.out_g[pp*8+1]+p.out_bb[pp*8+1];
    o0.z=(v[2]-m)*rs*p.out_g[pp*8+2]+p.out_bb[pp*8+2];
    o0.w=(v[3]-m)*rs*p.out_g[pp*8+3]+p.out_bb[pp*8+3];
    o1.x=(v[4]-m)*rs*p.out_g[pp*8+4]+p.out_bb[pp*8+4];
    o1.y=(v[5]-m)*rs*p.out_g[pp*8+5]+p.out_bb[pp*8+5];
    o1.z=(v[6]-m)*rs*p.out_g[pp*8+6]+p.out_bb[pp*8+6];
    o1.w=(v[7]-m)*rs*p.out_g[pp*8+7]+p.out_bb[pp*8+7];
    float* dst = p.outp + (size_t)(bB+b_)*128 + pp*8;
    *(float4*)dst = o0; *(float4*)(dst+4) = o1;
  }
}

// ---------------- host ----------------
extern "C" void kernel_launch(void* const* d_in, const int* in_sizes, int n_in,
                              void* d_out, int out_size, void* d_ws, size_t ws_size,
                              hipStream_t stream){
  (void)in_sizes; (void)n_in; (void)out_size;
  char* ws = (char*)d_ws;
  const size_t NEED1 = (size_t)B_*16384;   // dense nbg: 128 MiB

  P p;
  p.ego=(const float*)d_in[0]; p.epos=(const float*)d_in[1]; p.evel=(const float*)d_in[2];
  p.npos=(const float*)d_in[3]; p.nvel=(const float*)d_in[4]; p.mask=(const int*)d_in[5];
  p.npW=(const float*)d_in[6]; p.npb=(const float*)d_in[7]; p.npg=(const float*)d_in[8]; p.npbb=(const float*)d_in[9];
  p.ego_b=(const float*)d_in[11]; p.ego_g=(const float*)d_in[12]; p.ego_bb=(const float*)d_in[13];
  p.bo=(const float*)d_in[27]; p.b2=(const float*)d_in[31];
  p.out_b=(const float*)d_in[33]; p.out_g=(const float*)d_in[34]; p.out_bb=(const float*)d_in[35];
  p.nbg = (ushort*)ws;
  p.outp=(float*)d_out;

  #define PREP_ARGS p, \
      (const float*)d_in[20],(const float*)d_in[21],(const float*)d_in[14],(const float*)d_in[15], \
      (const float*)d_in[22],(const float*)d_in[23],(const float*)d_in[16],(const float*)d_in[17], \
      (const float*)d_in[24],(const float*)d_in[25], \
      (const float*)d_in[28],(const float*)d_in[29],(const float*)d_in[18],(const float*)d_in[19], \
      (const float*)d_in[26],(const float*)d_in[30],(const float*)d_in[10],(const float*)d_in[32]

  if (ws_size >= NEED1){
    prep_all<1><<<3713 + B_/2, 256, 0, stream>>>(PREP_ARGS);
    st_main6<<<B_/16,256,0,stream>>>(p);
  } else {
    prep_all<0><<<3713, 256, 0, stream>>>(PREP_ARGS);
    st_main0<<<B_/16,256,0,stream>>>(p);
  }
  #undef PREP_ARGS
}